// Round 10
// baseline (298.503 us; speedup 1.0000x reference)
//
#include <hip/hip_runtime.h>

// GIN: 3 layers of {agg = scatter_sum(h[src] -> dst); h = relu(((1+eps)h + agg) @ W + b)}
// then per-graph segment-sum readout (graph_ids sorted) -> 2-layer MLP.
//
// R23: A/B resolving R22's hidden layer regression (49.7 -> 67us when the
//      layer consumed slack-CSR + int2 metadata; BW 2.76->1.9 TB/s). Keep
//      R22's 7-dispatch chain, but csr_build now RE-PACKS slack buckets
//      into packed csr[0..E) + packed int offsets[N+1] (each block LDS-scans
//      the 196-entry cnt[] for its global base; offsets[N]=E falls out of
//      the scan). Layer kernel is byte-identical to R21's 49.7us binary.
//      Cost: +4.8MB read +4.8MB write inside an existing kernel (~+3us).
// R22: slack buckets kill pre-count+prefix kernels; readout+MLP fused;
//      non-layer 163 -> 95us. R21: cursor-reservation scatter.
// R18: flat-batch gather = layer floor (gather path saturated: R19 showed
//      occupancy 42->66% LOWERS BW; ILP closed R14-R18).
// R13: uniform-trip gather. R10: fused layer. R9: bucketed CSR. R7: f16 H.
// R5: MFMA bf16 hi/lo 3-product gemm.

#define NBLK 512     // edge chunks for bucket build
#define BS 512       // nodes per bucket (pow2)
#define CAPSH 13     // slack region: 8192 slots per bucket (bkt only)

typedef unsigned short ushort_t;
typedef __bf16 v8bf __attribute__((ext_vector_type(8)));
typedef float v4f __attribute__((ext_vector_type(4)));

__device__ __forceinline__ float h2f_lo(unsigned int v) {
    return (float)__builtin_bit_cast(_Float16, (unsigned short)(v & 0xffffu));
}
__device__ __forceinline__ float h2f_hi(unsigned int v) {
    return (float)__builtin_bit_cast(_Float16, (unsigned short)(v >> 16));
}
__device__ __forceinline__ unsigned int f2h(float f) {
    return (unsigned int)__builtin_bit_cast(unsigned short, (_Float16)f);
}

// A: scatter into slack bucket regions (blocks 0..NBLK-1) | x cast | W split.
__global__ __launch_bounds__(256) void scatter_pre_kernel(
        const int* __restrict__ src, const int* __restrict__ dst,
        int* __restrict__ cnt, unsigned int* __restrict__ bkt,
        int E, int nbkt, int ebpb,
        const float* __restrict__ x, ushort_t* __restrict__ xh, int n4, int castBlocks,
        const float* __restrict__ W, ushort_t* __restrict__ whi,
        ushort_t* __restrict__ wlo, int wtotal) {
    __shared__ int lcnt[256];
    __shared__ int lbase[256];
    __shared__ int lrank[256];
    int t = threadIdx.x;
    int blk = blockIdx.x;
    if (blk < NBLK) {
        lcnt[t] = 0; lrank[t] = 0;
        __syncthreads();
        int base = blk * ebpb;
        int end = min(base + ebpb, E);
        for (int i = base + t; i < end; i += 256)
            atomicAdd(&lcnt[dst[i] >> 9], 1);       // chunk fits L1/L2: cheap re-read
        __syncthreads();
        if (t < nbkt && lcnt[t])
            lbase[t] = (t << CAPSH) + atomicAdd(&cnt[t], lcnt[t]);
        __syncthreads();
        for (int i = base + t; i < end; i += 256) {
            int d = dst[i];
            int b = d >> 9;
            int r = atomicAdd(&lrank[b], 1);
            bkt[lbase[b] + r] = ((unsigned int)src[i] << 9) | (unsigned int)(d & (BS - 1));
        }
    } else if (blk < NBLK + castBlocks) {
        int i = (blk - NBLK) * 256 + t;
        if (i < n4) {
            float4 v = ((const float4*)x)[i];
            uint2 p;
            p.x = f2h(v.x) | (f2h(v.y) << 16);
            p.y = f2h(v.z) | (f2h(v.w) << 16);
            ((uint2*)xh)[i] = p;
        }
    } else {
        int i = (blk - NBLK - castBlocks) * 256 + t;
        if (i < wtotal) {
            int l = i >> 12, r = i & 4095;
            int n = r >> 6, k = r & 63;
            float w = W[l * 4096 + k * 64 + n];
            __bf16 h = (__bf16)w;
            float rem = w - (float)h;
            whi[i] = __builtin_bit_cast(ushort_t, h);
            wlo[i] = __builtin_bit_cast(ushort_t, (__bf16)rem);
        }
    }
}

// B: block b = bucket b. Global base from LDS scan of cnt[]; local hist +
// scan; emit PACKED offsets[N+1] (int) and PACKED csr[0..E) -- the exact
// R21 layer-input format. offsets[N]=E falls out of the last bucket's scan.
__global__ __launch_bounds__(256) void csr_build_kernel(
        const unsigned int* __restrict__ bkt, const int* __restrict__ cnt,
        int* __restrict__ offsets, int* __restrict__ csr, int N, int nbkt) {
    __shared__ int c0[BS];
    __shared__ int rk[BS];
    __shared__ int sh[256];
    int b = blockIdx.x, t = threadIdx.x;
    // global packed base for this bucket: exclusive prefix of cnt[0..b)
    int v = (t < nbkt) ? cnt[t] : 0;
    sh[t] = v;
    __syncthreads();
    for (int off = 1; off < 256; off <<= 1) {
        int u = (t >= off) ? sh[t - off] : 0;
        __syncthreads();
        sh[t] += u;
        __syncthreads();
    }
    int gbase = (b == 0) ? 0 : sh[b - 1];   // uniform broadcast read
    int cb = cnt[b];
    __syncthreads();
    c0[t] = 0; c0[t + 256] = 0;
    rk[t] = 0; rk[t + 256] = 0;
    __syncthreads();
    int sbase = b << CAPSH;
    for (int i = t; i < cb; i += 256)
        atomicAdd(&c0[bkt[sbase + i] & (BS - 1)], 1);
    __syncthreads();
    int i0 = 2 * t, i1 = 2 * t + 1;
    int v0 = c0[i0], v1 = c0[i1];
    int pair = v0 + v1;
    sh[t] = pair;
    __syncthreads();
    for (int off = 1; off < 256; off <<= 1) {
        int u = (t >= off) ? sh[t - off] : 0;
        __syncthreads();
        sh[t] += u;
        __syncthreads();
    }
    int ex = sh[t] - pair;
    __syncthreads();
    c0[i0] = ex;
    c0[i1] = ex + v0;
    __syncthreads();
    int d0 = (b << 9) + i0;
    if (d0 <= N) offsets[d0] = gbase + c0[i0];   // d0==N: c0 = cb -> offsets[N]=E
    int d1 = (b << 9) + i1;
    if (d1 <= N) offsets[d1] = gbase + c0[i1];
    for (int i = t; i < cb; i += 256) {
        unsigned int vv = bkt[sbase + i];
        int dl = vv & (BS - 1);
        int r = atomicAdd(&rk[dl], 1);
        csr[gbase + c0[dl] + r] = (int)(vv >> 9);
    }
}

// consume one node from a 6-slot register buffer (+tail fallback), reduce,
// self term, store row into wave-private LDS. kk must be a compile-time
// constant (unrolled caller) so idxa[kk]/buf[j] stay register-resident.
#define CONSUME_NODE(kk, dgv, e0v, buf, sf) { \
    float ax = 0.f, ay = 0.f, az = 0.f, aw = 0.f; \
    _Pragma("unroll") \
    for (int j = 0; j < 6; ++j) { \
        if (g + 4 * j < (dgv)) { \
            ax += h2f_lo(buf[j].x); ay += h2f_hi(buf[j].x); \
            az += h2f_lo(buf[j].y); aw += h2f_hi(buf[j].y); } } \
    if ((dgv) > 24) {                   /* rare tail (Poisson-12, ~0.1%) */ \
        int dc_ = min((dgv), 64); \
        for (int j = 24 + g; j < dc_; j += 4) { \
            int s_ = __shfl(idxa[kk], j, 64); \
            uint2 v_ = hp2[(size_t)s_ * 16 + sl]; \
            ax += h2f_lo(v_.x); ay += h2f_hi(v_.x); \
            az += h2f_lo(v_.y); aw += h2f_hi(v_.y); } \
        for (int j = 64 + g; j < (dgv); j += 4) {   /* astronomically rare */ \
            int s_ = csr[(e0v) + j]; \
            uint2 v_ = hp2[(size_t)s_ * 16 + sl]; \
            ax += h2f_lo(v_.x); ay += h2f_hi(v_.x); \
            az += h2f_lo(v_.y); aw += h2f_hi(v_.y); } } \
    ax += __shfl_xor(ax, 16, 64); ax += __shfl_xor(ax, 32, 64); \
    ay += __shfl_xor(ay, 16, 64); ay += __shfl_xor(ay, 32, 64); \
    az += __shfl_xor(az, 16, 64); az += __shfl_xor(az, 32, 64); \
    aw += __shfl_xor(aw, 16, 64); aw += __shfl_xor(aw, 32, 64); \
    if (tile * 16 + (kk) < N) { \
        ax = fmaf(eps1, h2f_lo(sf.x), ax); ay = fmaf(eps1, h2f_hi(sf.x), ay); \
        az = fmaf(eps1, h2f_lo(sf.y), az); aw = fmaf(eps1, h2f_hi(sf.y), aw); } \
    if (g == 0) { \
        float4 r4_; r4_.x = ax; r4_.y = ay; r4_.z = az; r4_.w = aw; \
        *(float4*)&myrows[(kk) * 64 + sl * 4] = r4_; } }

// Fused GIN layer, R18/R21 VERBATIM (the 49.7us binary): wave = 16-node
// tile; 16 idx loads upfront; 8 flat batches of 2 nodes; MFMA epilogue.
__global__ __launch_bounds__(256, 4) void layer_kernel(
        const ushort_t* __restrict__ hin, ushort_t* __restrict__ hout,
        const int* __restrict__ offsets, const int* __restrict__ csr,
        const ushort_t* __restrict__ wt_hi, const ushort_t* __restrict__ wt_lo,
        const float* __restrict__ gin_b, const float* __restrict__ eps_arr,
        int layer, int N, int E) {
    __shared__ float rows[4 * 16 * 64];   // 16KB: 4 waves x 16 nodes x 64 f32
    int t = threadIdx.x;
    int wv = t >> 6, lane = t & 63;
    int tile = blockIdx.x * 4 + wv;
    if (tile * 16 >= N) return;           // waves independent
    float* myrows = rows + wv * 16 * 64;
    const uint2* hp2 = (const uint2*)hin;
    float eps1 = 1.0f + eps_arr[layer];

    int g  = lane >> 4;    // edge group 0..3
    int sl = lane & 15;    // uint2 slot (dims 4sl..4sl+3)

    // one coalesced load covers all 17 offsets for this tile
    int off_l = offsets[min(tile * 16 + lane, N)];
    int e0a[17];
    #pragma unroll
    for (int k = 0; k < 17; ++k)
        e0a[k] = __builtin_amdgcn_readlane(off_l, k);

    // all 16 idx loads issued upfront: independent, clamped (deterministic),
    // masked at the select (which the compiler may sink -- loads stay early).
    int idxa[16];
    #pragma unroll
    for (int k = 0; k < 16; ++k) {
        int dg_ = e0a[k + 1] - e0a[k];
        int v_ = csr[min(e0a[k] + lane, E - 1)];
        idxa[k] = (lane < dg_) ? v_ : 0;
    }

    // 8 batches x 2 nodes: all 14 loads textually before any consumption.
    #pragma unroll
    for (int kb = 0; kb < 8; ++kb) {
        const int k = kb * 2;
        int e0A = e0a[k],     dgA = e0a[k + 1] - e0a[k];
        int e0B = e0a[k + 1], dgB = e0a[k + 2] - e0a[k + 1];
        uint2 b[6], c[6];
        #pragma unroll
        for (int j = 0; j < 6; ++j) {
            int p = g + 4 * j;
            int s = (p < dgA) ? __shfl(idxa[k], p, 64) : 0;
            b[j] = hp2[(size_t)s * 16 + sl];          // masked -> row 0 (L1)
        }
        #pragma unroll
        for (int j = 0; j < 6; ++j) {
            int p = g + 4 * j;
            int s = (p < dgB) ? __shfl(idxa[k + 1], p, 64) : 0;
            c[j] = hp2[(size_t)s * 16 + sl];
        }
        uint2 sfA = hp2[(size_t)min(tile * 16 + k,     N - 1) * 16 + sl];
        uint2 sfB = hp2[(size_t)min(tile * 16 + k + 1, N - 1) * 16 + sl];
        __builtin_amdgcn_sched_barrier(0);   // pin: loads above, consume below
        CONSUME_NODE(k,     dgA, e0A, b, sfA)
        CONSUME_NODE(k + 1, dgB, e0B, c, sfB)
    }
    // intra-wave LDS ordering: compiler emits lgkmcnt before reads; no barrier.

    int c2 = lane & 15;    // node within tile / n-index
    int q  = lane >> 4;    // quad
    int node16 = tile * 16 + c2;

    const ushort_t* Whi = wt_hi + layer * 4096;
    const ushort_t* Wlo = wt_lo + layer * 4096;
    const float*    bl  = gin_b + layer * 64;

    v8bf bhi[2], blo2[2];
    #pragma unroll
    for (int kt = 0; kt < 2; ++kt) {
        float4 f0 = *(float4*)&myrows[c2 * 64 + kt * 32 + q * 8];
        float4 f1 = *(float4*)&myrows[c2 * 64 + kt * 32 + q * 8 + 4];
        float xs[8] = {f0.x, f0.y, f0.z, f0.w, f1.x, f1.y, f1.z, f1.w};
        #pragma unroll
        for (int j = 0; j < 8; ++j) {
            __bf16 h = (__bf16)xs[j];
            bhi[kt][j] = h;
            blo2[kt][j] = (__bf16)(xs[j] - (float)h);
        }
    }

    #pragma unroll
    for (int mt = 0; mt < 4; ++mt) {
        v4f acc = {0.f, 0.f, 0.f, 0.f};
        #pragma unroll
        for (int kt = 0; kt < 2; ++kt) {
            int dim = mt * 16 + c2;
            size_t off = (size_t)dim * 64 + kt * 32 + q * 8;
            v8bf ah = __builtin_bit_cast(v8bf, *(const uint4*)(Whi + off));
            v8bf al = __builtin_bit_cast(v8bf, *(const uint4*)(Wlo + off));
            acc = __builtin_amdgcn_mfma_f32_16x16x32_bf16(ah, bhi[kt],  acc, 0, 0, 0);
            acc = __builtin_amdgcn_mfma_f32_16x16x32_bf16(ah, blo2[kt], acc, 0, 0, 0);
            acc = __builtin_amdgcn_mfma_f32_16x16x32_bf16(al, bhi[kt],  acc, 0, 0, 0);
        }
        float4 bv = ((const float4*)(bl + mt * 16))[q];
        float o0 = fmaxf(acc[0] + bv.x, 0.f);
        float o1 = fmaxf(acc[1] + bv.y, 0.f);
        float o2 = fmaxf(acc[2] + bv.z, 0.f);
        float o3 = fmaxf(acc[3] + bv.w, 0.f);
        uint2 pk;
        pk.x = f2h(o0) | (f2h(o1) << 16);
        pk.y = f2h(o2) | (f2h(o3) << 16);
        if (node16 < N)
            *(uint2*)(hout + (size_t)node16 * 64 + mt * 16 + q * 4) = pk;
    }
}

// Fused readout + MLP: block = graph, 384 threads = 6 waves (layer l = w>>1,
// node-parity p = w&1). Each wave sums 4 nodes/iter via uint2, shfl_xor
// reduce, LDS combine across parities, then the 2-layer MLP.
__global__ __launch_bounds__(384) void readout_mlp_kernel(
        const ushort_t* __restrict__ H, const int* __restrict__ gids,
        const float* __restrict__ W1, const float* __restrict__ b1,
        const float* __restrict__ W2, const float* __restrict__ b2,
        float* __restrict__ out, int N) {
    __shared__ float part[6][64];
    __shared__ float gr[192];
    __shared__ float hid[128];
    int graph = blockIdx.x;
    int t = threadIdx.x;
    int w = t >> 6, lane = t & 63;
    int l = w >> 1, p = w & 1;
    int lo = 0, hi = N;
    while (lo < hi) { int m = (lo + hi) >> 1; if (gids[m] < graph) lo = m + 1; else hi = m; }
    int start = lo;
    int lo2 = start, hi2 = N;
    while (lo2 < hi2) { int m = (lo2 + hi2) >> 1; if (gids[m] < graph + 1) lo2 = m + 1; else hi2 = m; }
    int end = lo2;
    int nd  = lane >> 4;            // node-phase 0..3
    int slp = lane & 15;            // uint2 slot (dims 4slp..4slp+3)
    float a0 = 0.f, a1 = 0.f, a2 = 0.f, a3 = 0.f;
    const uint2* Hl = (const uint2*)(H + (size_t)l * N * 64);
    for (int n = start + p * 4 + nd; n < end; n += 8) {
        uint2 v = Hl[(size_t)n * 16 + slp];
        a0 += h2f_lo(v.x); a1 += h2f_hi(v.x);
        a2 += h2f_lo(v.y); a3 += h2f_hi(v.y);
    }
    a0 += __shfl_xor(a0, 16, 64); a0 += __shfl_xor(a0, 32, 64);
    a1 += __shfl_xor(a1, 16, 64); a1 += __shfl_xor(a1, 32, 64);
    a2 += __shfl_xor(a2, 16, 64); a2 += __shfl_xor(a2, 32, 64);
    a3 += __shfl_xor(a3, 16, 64); a3 += __shfl_xor(a3, 32, 64);
    if (lane < 16) {
        float4 r4; r4.x = a0; r4.y = a1; r4.z = a2; r4.w = a3;
        *(float4*)&part[w][slp * 4] = r4;
    }
    __syncthreads();
    if (t < 192) {
        int ll = t >> 6, d = t & 63;
        gr[t] = part[ll * 2][d] + part[ll * 2 + 1][d];
    }
    __syncthreads();
    if (t < 128) {
        float s = b1[t];
        for (int k = 0; k < 192; ++k) s = fmaf(gr[k], W1[k * 128 + t], s);
        hid[t] = fmaxf(s, 0.0f);
    }
    __syncthreads();
    if (t < 32) {
        float s = b2[t];
        for (int k = 0; k < 128; ++k) s = fmaf(hid[k], W2[k * 32 + t], s);
        out[graph * 32 + t] = s;
    }
}

extern "C" void kernel_launch(void* const* d_in, const int* in_sizes, int n_in,
                              void* d_out, int out_size, void* d_ws, size_t ws_size,
                              hipStream_t stream) {
    const float* x     = (const float*)d_in[0];
    const float* gin_W = (const float*)d_in[1];
    const float* gin_b = (const float*)d_in[2];
    const float* eps   = (const float*)d_in[3];
    const float* r_W1  = (const float*)d_in[4];
    const float* r_b1  = (const float*)d_in[5];
    const float* r_W2  = (const float*)d_in[6];
    const float* r_b2  = (const float*)d_in[7];
    const int*   src   = (const int*)d_in[8];
    const int*   dst   = (const int*)d_in[9];
    const int*   gids  = (const int*)d_in[10];

    int N = in_sizes[0] / 64;       // 100000
    int E = in_sizes[8];            // 1200000
    int B = out_size / 32;          // 256

    int nbkt = (N + BS - 1) / BS;   // 196 (<= 256)
    int ebpb = (E + NBLK - 1) / NBLK;
    int n4 = N * 64 / 4;
    int castBlocks = (n4 + 255) / 256;
    int wtotal = 3 * 4096;
    int prepBlocks = (wtotal + 255) / 256;
    int bktTot = nbkt << CAPSH;     // slack bkt size (196*8192)

    // workspace layout (4B words), all regions fully written before read:
    //   cnt[nbkt] | offsets[N+1] | bkt[nbkt<<13] | csr[E] | pad
    //   xh[N*64 f16] | H[3*N*64 f16] | whi[3*4096] | wlo[3*4096]
    int* ws       = (int*)d_ws;
    int* cnt      = ws;
    int* offsets  = cnt + nbkt;
    unsigned int* bkt = (unsigned int*)(offsets + (N + 1));
    int* csr      = (int*)(bkt + bktTot);
    size_t w      = (size_t)(csr + E - ws);
    w = (w + 15) & ~(size_t)15;     // 64B align
    ushort_t* xh  = (ushort_t*)(ws + w);
    ushort_t* H   = xh + (size_t)N * 64;
    ushort_t* whi = H + 3 * (size_t)N * 64;
    ushort_t* wlo = whi + 3 * 4096;

    hipMemsetAsync(cnt, 0, nbkt * sizeof(int), stream);    // capturable memset
    scatter_pre_kernel<<<NBLK + castBlocks + prepBlocks, 256, 0, stream>>>(
        src, dst, cnt, bkt, E, nbkt, ebpb,
        x, xh, n4, castBlocks, gin_W, whi, wlo, wtotal);
    csr_build_kernel<<<nbkt, 256, 0, stream>>>(bkt, cnt, offsets, csr, N, nbkt);

    int lbk = (N + 63) / 64;        // 4 tiles (waves) of 16 nodes per block
    ushort_t* H0 = H;
    ushort_t* H1 = H + (size_t)N * 64;
    ushort_t* H2 = H + 2 * (size_t)N * 64;

    layer_kernel<<<lbk, 256, 0, stream>>>(xh, H0, offsets, csr, whi, wlo, gin_b, eps, 0, N, E);
    layer_kernel<<<lbk, 256, 0, stream>>>(H0, H1, offsets, csr, whi, wlo, gin_b, eps, 1, N, E);
    layer_kernel<<<lbk, 256, 0, stream>>>(H1, H2, offsets, csr, whi, wlo, gin_b, eps, 2, N, E);

    readout_mlp_kernel<<<B, 384, 0, stream>>>(H, gids, r_W1, r_b1, r_W2, r_b2, (float*)d_out, N);
}